// Round 9
// baseline (396.514 us; speedup 1.0000x reference)
//
#include <hip/hip_runtime.h>
#include <hip/hip_bf16.h>
#include <math.h>

static constexpr int NN  = 1000000;   // nodes
static constexpr int HD  = 128;       // memory dim
static constexpr int ED  = 64;        // edge dim
static constexpr int TD  = 16;        // time dim
static constexpr int NE  = 100000;    // events
static constexpr int GIN = 336;       // 2*HD + ED + TD
static constexpr int KP  = 352;       // GIN padded to mult of 32
static constexpr int KS  = KP / 32;   // 11 K-steps
static constexpr int EB  = 32;        // events per gru block (2 tiles of 16)
static constexpr int PS  = 264;       // pred LDS row stride in shorts
static constexpr int NBG = NE / EB;   // 3125 gru/gather/pred blocks
static constexpr int NBC = 2 * NBG;   // 6250 copy blocks
static constexpr int CR  = NN / NBC;  // 160 rows per copy block
static constexpr int NIH = 24 * KS * 512;  // 135168
static constexpr int NHH = 24 * 4 * 512;   //  49152
static constexpr int NP1 = 8 * 8 * 512;    //  32768
static constexpr int NBW = (NE + 511) / 512;        // 196 winflag blocks
static constexpr int NBV = (NIH + NHH + NP1) / 512; // 424 wconv blocks

typedef __attribute__((ext_vector_type(8))) short bf16x8;
typedef __attribute__((ext_vector_type(4))) float f32x4;

__device__ inline unsigned f2bf(float x) {
    union { float f; unsigned u; } a; a.f = x;
    unsigned r = a.u + 0x7fff + ((a.u >> 16) & 1);   // RNE
    return r >> 16;
}
__device__ inline float bf2f(unsigned short u) {
    union { unsigned u; float f; } a; a.u = ((unsigned)u) << 16; return a.f;
}
// native 3-instruction sigmoid/tanh (v_exp_f32 = 2^x, v_rcp_f32)
__device__ inline float fsig(float x) {
    return __builtin_amdgcn_rcpf(1.f + __builtin_amdgcn_exp2f(x * -1.44269504f));
}
__device__ inline float ftanh(float x) {
    return 1.f - 2.f * __builtin_amdgcn_rcpf(1.f + __builtin_amdgcn_exp2f(x * 2.88539008f));
}

// ---------------- priority pass: last-write-wins resolution ----------------
__global__ void prio_kernel(const int* __restrict__ src, const int* __restrict__ dst,
                            int* __restrict__ prio) {
    int e = blockIdx.x * blockDim.x + threadIdx.x;
    if (e < NE) {
        atomicMax(&prio[src[e]], e);
        atomicMax(&prio[dst[e]], NE + e);
    }
}

// ---- prep kernel: {gather-pack | winflag | wconv} by block range (no copy) ----
__global__ __launch_bounds__(512) void prep_kernel(
    const float* __restrict__ memory,
    const int* __restrict__ src, const int* __restrict__ dst,
    const float* __restrict__ ts, const float* __restrict__ ef,
    const float* __restrict__ W_time, const float* __restrict__ b_time,
    const float* __restrict__ W_ih, const float* __restrict__ W_hh,
    const float* __restrict__ W_p1,
    const int* __restrict__ prio, unsigned char* __restrict__ win,
    unsigned short* __restrict__ A_pack,
    unsigned short* __restrict__ Wihf, unsigned short* __restrict__ Whhf,
    unsigned short* __restrict__ Wp1f)
{
    const int bid = blockIdx.x;
    const int tid = threadIdx.x;

    if (bid < NBG) {
        // ---- gather + time-enc + bf16 pack into A_pack[e][352] ----
        const int e0 = bid * EB;
        for (int idx = tid; idx < EB * 88; idx += 512) {
            int e = idx / 88, c4 = idx % 88;
            float4 v = {0.f, 0.f, 0.f, 0.f};
            if (c4 < 32)      v = ((const float4*)&memory[(size_t)src[e0 + e] * HD])[c4];
            else if (c4 < 64) v = ((const float4*)&memory[(size_t)dst[e0 + e] * HD])[c4 - 32];
            else if (c4 < 80) v = ((const float4*)&ef[(size_t)(e0 + e) * ED])[c4 - 64];
            else if (c4 < 84) {
                int j = (c4 - 80) * 4;
                float t = ts[e0 + e];
                v.x = __sinf(t * W_time[j]     + b_time[j]);
                v.y = __sinf(t * W_time[j + 1] + b_time[j + 1]);
                v.z = __sinf(t * W_time[j + 2] + b_time[j + 2]);
                v.w = __sinf(t * W_time[j + 3] + b_time[j + 3]);
            }
            uint2 p;
            p.x = f2bf(v.x) | (f2bf(v.y) << 16);
            p.y = f2bf(v.z) | (f2bf(v.w) << 16);
            *(uint2*)&A_pack[(size_t)(e0 + e) * KP + c4 * 4] = p;
        }
    } else if (bid < NBG + NBW) {
        // ---- per-event winner flags ----
        int e = (bid - NBG) * 512 + tid;
        if (e < NE)
            win[e] = (unsigned char)((prio[src[e]] == e ? 1 : 0) |
                                     (prio[dst[e]] == NE + e ? 2 : 0));
    } else {
        // ---- weight repack: f32 -> bf16, MFMA-fragment-linear ----
        int q = (bid - NBG - NBW) * 512 + tid;
        if (q < NIH) {
            int t = q / (KS * 512), rem = q % (KS * 512);
            int kk = rem / 512, li = rem % 512;
            int l = li >> 3, j = li & 7;
            int row = t * 16 + (l & 15);
            int col = kk * 32 + (l >> 4) * 8 + j;
            Wihf[q] = (col < GIN) ? (unsigned short)f2bf(W_ih[(size_t)row * GIN + col])
                                  : (unsigned short)0;
        } else if (q < NIH + NHH) {
            int p = q - NIH;
            int t = p / (4 * 512), rem = p % (4 * 512);
            int kk = rem / 512, li = rem % 512;
            int l = li >> 3, j = li & 7;
            int row = t * 16 + (l & 15);
            int col = kk * 32 + (l >> 4) * 8 + j;
            Whhf[p] = (unsigned short)f2bf(W_hh[(size_t)row * HD + col]);
        } else {
            int p = q - NIH - NHH;
            int w = p / (8 * 512), rem = p % (8 * 512);
            int kk = rem / 512, li = rem % 512;
            int l = li >> 3, j = li & 7;
            int row = w * 16 + (l & 15);
            int col = kk * 32 + (l >> 4) * 8 + j;
            Wp1f[p] = (unsigned short)f2bf(W_p1[(size_t)row * (2 * HD) + col]);
        }
    }
}

// ---- MFMA GRU on packed A + winner scatter (unchanged from r8) ----
__global__ __launch_bounds__(512) void gru_kernel(
    const unsigned short* __restrict__ A_pack,
    const int* __restrict__ src, const int* __restrict__ dst,
    const unsigned short* __restrict__ Wihf, const unsigned short* __restrict__ Whhf,
    const float* __restrict__ b_ih, const float* __restrict__ b_hh,
    const unsigned char* __restrict__ win, float* __restrict__ mem_out)
{
    __shared__ unsigned short a_lds[EB * KP];        // 22528 B
    const int tid = threadIdx.x;
    const int e0  = blockIdx.x * EB;

    {
        const uint4* g4 = (const uint4*)(A_pack + (size_t)e0 * KP);
        uint4* l4 = (uint4*)a_lds;
        for (int i = tid; i < EB * KP / 8; i += 512)   // 1408 uint4
            l4[i] = g4[i];
    }
    __syncthreads();

    const int w    = tid >> 6;
    const int lane = tid & 63;
    const int lg   = lane >> 4;
    const int u    = w * 16 + (lane & 15);           // output unit
    const int arow = lane & 15;

#define ALD(t, kkk) (*(const bf16x8*)&a_lds[(arow + (t) * 16) * KP + (kkk) * 32 + lg * 8])

    f32x4 z4 = {0.f, 0.f, 0.f, 0.f};
    f32x4 ir0 = z4, ir1 = z4, iz0 = z4, iz1 = z4, in0 = z4, in1 = z4;
    f32x4 sr0 = z4, sr1 = z4, sz0 = z4, sz1 = z4, sn0 = z4, sn1 = z4;
    f32x4 dr0 = z4, dr1 = z4, dz0 = z4, dz1 = z4, dn0 = z4, dn1 = z4;

#pragma unroll
    for (int kk = 0; kk < KS; ++kk) {   // gi = inp @ W_ih^T
        bf16x8 b0 = *(const bf16x8*)&Wihf[(((size_t)(0 * 8 + w) * KS + kk) * 64 + lane) * 8];
        bf16x8 b1 = *(const bf16x8*)&Wihf[(((size_t)(1 * 8 + w) * KS + kk) * 64 + lane) * 8];
        bf16x8 b2 = *(const bf16x8*)&Wihf[(((size_t)(2 * 8 + w) * KS + kk) * 64 + lane) * 8];
        bf16x8 a0 = ALD(0, kk), a1 = ALD(1, kk);
        ir0 = __builtin_amdgcn_mfma_f32_16x16x32_bf16(a0, b0, ir0, 0, 0, 0);
        ir1 = __builtin_amdgcn_mfma_f32_16x16x32_bf16(a1, b0, ir1, 0, 0, 0);
        iz0 = __builtin_amdgcn_mfma_f32_16x16x32_bf16(a0, b1, iz0, 0, 0, 0);
        iz1 = __builtin_amdgcn_mfma_f32_16x16x32_bf16(a1, b1, iz1, 0, 0, 0);
        in0 = __builtin_amdgcn_mfma_f32_16x16x32_bf16(a0, b2, in0, 0, 0, 0);
        in1 = __builtin_amdgcn_mfma_f32_16x16x32_bf16(a1, b2, in1, 0, 0, 0);
    }
#pragma unroll
    for (int kk = 0; kk < 4; ++kk) {    // gh_s (A=s) and gh_d (A=d) share W_hh frags
        bf16x8 c0 = *(const bf16x8*)&Whhf[(((size_t)(0 * 8 + w) * 4 + kk) * 64 + lane) * 8];
        bf16x8 c1 = *(const bf16x8*)&Whhf[(((size_t)(1 * 8 + w) * 4 + kk) * 64 + lane) * 8];
        bf16x8 c2 = *(const bf16x8*)&Whhf[(((size_t)(2 * 8 + w) * 4 + kk) * 64 + lane) * 8];
        bf16x8 as0 = ALD(0, kk),     as1 = ALD(1, kk);
        bf16x8 ad0 = ALD(0, kk + 4), ad1 = ALD(1, kk + 4);
        sr0 = __builtin_amdgcn_mfma_f32_16x16x32_bf16(as0, c0, sr0, 0, 0, 0);
        sr1 = __builtin_amdgcn_mfma_f32_16x16x32_bf16(as1, c0, sr1, 0, 0, 0);
        dr0 = __builtin_amdgcn_mfma_f32_16x16x32_bf16(ad0, c0, dr0, 0, 0, 0);
        dr1 = __builtin_amdgcn_mfma_f32_16x16x32_bf16(ad1, c0, dr1, 0, 0, 0);
        sz0 = __builtin_amdgcn_mfma_f32_16x16x32_bf16(as0, c1, sz0, 0, 0, 0);
        sz1 = __builtin_amdgcn_mfma_f32_16x16x32_bf16(as1, c1, sz1, 0, 0, 0);
        dz0 = __builtin_amdgcn_mfma_f32_16x16x32_bf16(ad0, c1, dz0, 0, 0, 0);
        dz1 = __builtin_amdgcn_mfma_f32_16x16x32_bf16(ad1, c1, dz1, 0, 0, 0);
        sn0 = __builtin_amdgcn_mfma_f32_16x16x32_bf16(as0, c2, sn0, 0, 0, 0);
        sn1 = __builtin_amdgcn_mfma_f32_16x16x32_bf16(as1, c2, sn1, 0, 0, 0);
        dn0 = __builtin_amdgcn_mfma_f32_16x16x32_bf16(ad0, c2, dn0, 0, 0, 0);
        dn1 = __builtin_amdgcn_mfma_f32_16x16x32_bf16(ad1, c2, dn1, 0, 0, 0);
    }
#undef ALD

    const float bir = b_ih[u], biz = b_ih[u + 128], bin_ = b_ih[u + 256];
    const float bhr = b_hh[u], bhz = b_hh[u + 128], bhn = b_hh[u + 256];

    auto epilogue = [&](int t, f32x4 ir, f32x4 iz, f32x4 in_,
                        f32x4 sr, f32x4 sz, f32x4 sn,
                        f32x4 dr, f32x4 dz, f32x4 dn) {
#pragma unroll
        for (int j = 0; j < 4; ++j) {
            int el = t * 16 + lg * 4 + j, e = e0 + el;   // C/D: row=(lane>>4)*4+reg
            unsigned char wf = win[e];
            float gr_ = ir[j] + bir, gz_ = iz[j] + biz, gn_ = in_[j] + bin_;
            if (wf & 1) {   // src update wins
                float r = fsig(gr_ + sr[j] + bhr);
                float z = fsig(gz_ + sz[j] + bhz);
                float n = ftanh(gn_ + r * (sn[j] + bhn));
                float h = bf2f(a_lds[el * KP + u]);
                mem_out[(size_t)src[e] * HD + u] = (1.f - z) * n + z * h;
            }
            if (wf & 2) {   // dst update wins
                float r = fsig(gr_ + dr[j] + bhr);
                float z = fsig(gz_ + dz[j] + bhz);
                float n = ftanh(gn_ + r * (dn[j] + bhn));
                float h = bf2f(a_lds[el * KP + 128 + u]);
                mem_out[(size_t)dst[e] * HD + u] = (1.f - z) * n + z * h;
            }
        }
    };
    epilogue(0, ir0, iz0, in0, sr0, sz0, sn0, dr0, dz0, dn0);
    epilogue(1, ir1, iz1, in1, sr1, sz1, sn1, dr1, dz1, dn1);
}

// ---- final fat kernel: {copy ∥ pred} interleaved by bid%3 ----
// copy blocks (2/3): stream untouched rows (prio<0) memory->mem_out.
// pred blocks (1/3): MFMA predictor on winner rows (written by gru; disjoint
// from copy's rows). Both block classes are short -> no slow-block pile-up.
__global__ __launch_bounds__(512) void fat_kernel(
    const float* __restrict__ memory,
    const int* __restrict__ src, const int* __restrict__ dst,
    const unsigned short* __restrict__ Wp1f, const float* __restrict__ b_p1,
    const float* __restrict__ W_p2, const float* __restrict__ b_p2,
    const int* __restrict__ prio,
    float* __restrict__ mem_out, float* __restrict__ pred)
{
    __shared__ unsigned short h_lds[32 * PS];        // 16896 B (pred path only)
    __shared__ float partial[32][8];
    const int bid = blockIdx.x;
    const int tid = threadIdx.x;

    if (bid % 3 != 1) {
        // ---------------- copy path ----------------
        const int cb = (bid / 3) * 2 + (bid % 3 == 2 ? 1 : 0);   // 0..NBC-1
        const float4* in4  = (const float4*)memory;
        float4*       out4 = (float4*)mem_out;
        const int rbase = cb * CR;
        for (int i = tid; i < CR * 32; i += 512) {
            int r = rbase + (i >> 5);
            if (prio[r] < 0)
                out4[(size_t)r * 32 + (i & 31)] = in4[(size_t)r * 32 + (i & 31)];
        }
        return;
    }

    // ---------------- pred path ----------------
    const int e0 = (bid / 3) * 32;

    // stage h = [mem[src] | mem[dst]] as bf16
    for (int idx = tid; idx < 32 * 64; idx += 512) {
        int e = idx >> 6, p = idx & 63;
        const float4* row = (p < 32) ? (const float4*)&mem_out[(size_t)src[e0 + e] * HD]
                                     : (const float4*)&mem_out[(size_t)dst[e0 + e] * HD];
        float4 v = row[p & 31];
        int col = (p < 32 ? 0 : 128) + (p & 31) * 4;
        uint2 q;
        q.x = f2bf(v.x) | (f2bf(v.y) << 16);
        q.y = f2bf(v.z) | (f2bf(v.w) << 16);
        *(uint2*)&h_lds[e * PS + col] = q;
    }
    __syncthreads();

    const int w    = tid >> 6;
    const int lane = tid & 63;
    const int lg   = lane >> 4;
    const int u    = w * 16 + (lane & 15);

    f32x4 p0 = {0.f, 0.f, 0.f, 0.f}, p1 = p0;
#pragma unroll
    for (int kk = 0; kk < 8; ++kk) {
        bf16x8 b  = *(const bf16x8*)&Wp1f[(((size_t)w * 8 + kk) * 64 + lane) * 8];
        bf16x8 a0 = *(const bf16x8*)&h_lds[(lane & 15) * PS + kk * 32 + lg * 8];
        bf16x8 a1 = *(const bf16x8*)&h_lds[((lane & 15) + 16) * PS + kk * 32 + lg * 8];
        p0 = __builtin_amdgcn_mfma_f32_16x16x32_bf16(a0, b, p0, 0, 0, 0);
        p1 = __builtin_amdgcn_mfma_f32_16x16x32_bf16(a1, b, p1, 0, 0, 0);
    }
    const float bp = b_p1[u], w2 = W_p2[u];

    auto reduce_tile = [&](int t, f32x4 acc) {
#pragma unroll
        for (int j = 0; j < 4; ++j) {
            float v = acc[j] + bp;
            v = (v > 0.f ? v : 0.f) * w2;
            v += __shfl_xor(v, 1, 64);
            v += __shfl_xor(v, 2, 64);
            v += __shfl_xor(v, 4, 64);
            v += __shfl_xor(v, 8, 64);
            if ((lane & 15) == 0) partial[t * 16 + lg * 4 + j][w] = v;
        }
    };
    reduce_tile(0, p0);
    reduce_tile(1, p1);
    __syncthreads();

    if (tid < 32) {
        float s = b_p2[0];
#pragma unroll
        for (int q = 0; q < 8; ++q) s += partial[tid][q];
        pred[e0 + tid] = s;
    }
}

extern "C" void kernel_launch(void* const* d_in, const int* in_sizes, int n_in,
                              void* d_out, int out_size, void* d_ws, size_t ws_size,
                              hipStream_t stream) {
    const float* memory = (const float*)d_in[0];
    const int*   src    = (const int*)d_in[1];
    const int*   dst    = (const int*)d_in[2];
    const float* ts     = (const float*)d_in[3];
    const float* ef     = (const float*)d_in[4];
    const float* W_time = (const float*)d_in[5];
    const float* b_time = (const float*)d_in[6];
    const float* W_ih   = (const float*)d_in[7];
    const float* W_hh   = (const float*)d_in[8];
    const float* b_ih   = (const float*)d_in[9];
    const float* b_hh   = (const float*)d_in[10];
    const float* W_p1   = (const float*)d_in[11];
    const float* b_p1   = (const float*)d_in[12];
    const float* W_p2   = (const float*)d_in[13];
    const float* b_p2   = (const float*)d_in[14];

    float* pred    = (float*)d_out;                 // [NE]
    float* mem_out = pred + NE;                     // [NN, HD]

    char* ws = (char*)d_ws;
    int* prio            = (int*)ws;                ws += (size_t)NN * 4;
    unsigned short* Wihf = (unsigned short*)ws;     ws += (size_t)NIH * 2;
    unsigned short* Whhf = (unsigned short*)ws;     ws += (size_t)NHH * 2;
    unsigned short* Wp1f = (unsigned short*)ws;     ws += (size_t)NP1 * 2;
    unsigned char* win   = (unsigned char*)ws;      ws += 100352;        // 16B-aligned after
    unsigned short* A_pack = (unsigned short*)ws;   // [NE][KP] bf16, ~70.4 MB

    hipMemsetAsync(prio, 0xFF, (size_t)NN * sizeof(int), stream);   // -1
    prio_kernel<<<(NE + 255) / 256, 256, 0, stream>>>(src, dst, prio);
    prep_kernel<<<NBG + NBW + NBV, 512, 0, stream>>>(
        memory, src, dst, ts, ef, W_time, b_time, W_ih, W_hh, W_p1,
        prio, win, A_pack, Wihf, Whhf, Wp1f);
    gru_kernel<<<NBG, 512, 0, stream>>>(A_pack, src, dst, Wihf, Whhf,
                                        b_ih, b_hh, win, mem_out);
    fat_kernel<<<NBG + NBC, 512, 0, stream>>>(
        memory, src, dst, Wp1f, b_p1, W_p2, b_p2, prio, mem_out, pred);
}

// Round 10
// 385.628 us; speedup vs baseline: 1.0282x; 1.0282x over previous
//
#include <hip/hip_runtime.h>
#include <hip/hip_bf16.h>
#include <math.h>

static constexpr int NN  = 1000000;   // nodes
static constexpr int HD  = 128;       // memory dim
static constexpr int ED  = 64;        // edge dim
static constexpr int TD  = 16;        // time dim
static constexpr int NE  = 100000;    // events
static constexpr int GIN = 336;       // 2*HD + ED + TD
static constexpr int KP  = 352;       // GIN padded to mult of 32
static constexpr int KS  = KP / 32;   // 11 K-steps
static constexpr int EB  = 32;        // events per gru block (2 tiles of 16)
static constexpr int PS  = 264;       // pred LDS row stride in shorts
static constexpr int NBG = NE / EB;   // 3125 gru/gather blocks
static constexpr int NBC = 2 * NBG;   // 6250 copy blocks
static constexpr int CR  = NN / NBC;  // 160 rows per copy block
static constexpr int NIH = 24 * KS * 512;  // 135168
static constexpr int NHH = 24 * 4 * 512;   //  49152
static constexpr int NP1 = 8 * 8 * 512;    //  32768
static constexpr int NBW = (NE + 511) / 512;        // 196 winflag blocks
static constexpr int NBV = (NIH + NHH + NP1) / 512; // 424 wconv blocks

typedef __attribute__((ext_vector_type(8))) short bf16x8;
typedef __attribute__((ext_vector_type(4))) float f32x4;

__device__ inline unsigned f2bf(float x) {
    union { float f; unsigned u; } a; a.f = x;
    unsigned r = a.u + 0x7fff + ((a.u >> 16) & 1);   // RNE
    return r >> 16;
}
__device__ inline float bf2f(unsigned short u) {
    union { unsigned u; float f; } a; a.u = ((unsigned)u) << 16; return a.f;
}
// native 3-instruction sigmoid/tanh (v_exp_f32 = 2^x, v_rcp_f32)
__device__ inline float fsig(float x) {
    return __builtin_amdgcn_rcpf(1.f + __builtin_amdgcn_exp2f(x * -1.44269504f));
}
__device__ inline float ftanh(float x) {
    return 1.f - 2.f * __builtin_amdgcn_rcpf(1.f + __builtin_amdgcn_exp2f(x * 2.88539008f));
}

// ---------------- priority pass: last-write-wins resolution ----------------
__global__ void prio_kernel(const int* __restrict__ src, const int* __restrict__ dst,
                            int* __restrict__ prio) {
    int e = blockIdx.x * blockDim.x + threadIdx.x;
    if (e < NE) {
        atomicMax(&prio[src[e]], e);
        atomicMax(&prio[dst[e]], NE + e);
    }
}

// ---- prep kernel: {copy, copy, gather-pack} interleaved + winflag + wconv ----
// All paths: pure streaming, no LDS, no barriers -> near-HBM-BW.
// Copy is prio-guarded: winner rows (18.4%) are skipped -- gru's scatter owns them.
__global__ __launch_bounds__(512) void prep_kernel(
    const float* __restrict__ memory,
    const int* __restrict__ src, const int* __restrict__ dst,
    const float* __restrict__ ts, const float* __restrict__ ef,
    const float* __restrict__ W_time, const float* __restrict__ b_time,
    const float* __restrict__ W_ih, const float* __restrict__ W_hh,
    const float* __restrict__ W_p1,
    const int* __restrict__ prio, unsigned char* __restrict__ win,
    unsigned short* __restrict__ A_pack,
    unsigned short* __restrict__ Wihf, unsigned short* __restrict__ Whhf,
    unsigned short* __restrict__ Wp1f,
    float* __restrict__ mem_out)
{
    const int bid = blockIdx.x;
    const int tid = threadIdx.x;

    if (bid < NBC + NBG) {
        if (bid % 3 != 2) {
            // ---- prio-guarded copy of untouched rows ----
            const int cb = (bid / 3) * 2 + (bid % 3);
            const float4* in4  = (const float4*)memory;
            float4*       out4 = (float4*)mem_out;
            const int rbase = cb * CR;
            for (int i = tid; i < CR * 32; i += 512) {
                int r = rbase + (i >> 5);
                if (prio[r] < 0)
                    out4[(size_t)r * 32 + (i & 31)] = in4[(size_t)r * 32 + (i & 31)];
            }
        } else {
            // ---- gather + time-enc + bf16 pack into A_pack[e][352] ----
            const int e0 = (bid / 3) * EB;
            for (int idx = tid; idx < EB * 88; idx += 512) {
                int e = idx / 88, c4 = idx % 88;
                float4 v = {0.f, 0.f, 0.f, 0.f};
                if (c4 < 32)      v = ((const float4*)&memory[(size_t)src[e0 + e] * HD])[c4];
                else if (c4 < 64) v = ((const float4*)&memory[(size_t)dst[e0 + e] * HD])[c4 - 32];
                else if (c4 < 80) v = ((const float4*)&ef[(size_t)(e0 + e) * ED])[c4 - 64];
                else if (c4 < 84) {
                    int j = (c4 - 80) * 4;
                    float t = ts[e0 + e];
                    v.x = __sinf(t * W_time[j]     + b_time[j]);
                    v.y = __sinf(t * W_time[j + 1] + b_time[j + 1]);
                    v.z = __sinf(t * W_time[j + 2] + b_time[j + 2]);
                    v.w = __sinf(t * W_time[j + 3] + b_time[j + 3]);
                }
                uint2 p;
                p.x = f2bf(v.x) | (f2bf(v.y) << 16);
                p.y = f2bf(v.z) | (f2bf(v.w) << 16);
                *(uint2*)&A_pack[(size_t)(e0 + e) * KP + c4 * 4] = p;
            }
        }
    } else if (bid < NBC + NBG + NBW) {
        // ---- per-event winner flags ----
        int e = (bid - NBC - NBG) * 512 + tid;
        if (e < NE)
            win[e] = (unsigned char)((prio[src[e]] == e ? 1 : 0) |
                                     (prio[dst[e]] == NE + e ? 2 : 0));
    } else {
        // ---- weight repack: f32 -> bf16, MFMA-fragment-linear ----
        int q = (bid - NBC - NBG - NBW) * 512 + tid;
        if (q < NIH) {
            int t = q / (KS * 512), rem = q % (KS * 512);
            int kk = rem / 512, li = rem % 512;
            int l = li >> 3, j = li & 7;
            int row = t * 16 + (l & 15);
            int col = kk * 32 + (l >> 4) * 8 + j;
            Wihf[q] = (col < GIN) ? (unsigned short)f2bf(W_ih[(size_t)row * GIN + col])
                                  : (unsigned short)0;
        } else if (q < NIH + NHH) {
            int p = q - NIH;
            int t = p / (4 * 512), rem = p % (4 * 512);
            int kk = rem / 512, li = rem % 512;
            int l = li >> 3, j = li & 7;
            int row = t * 16 + (l & 15);
            int col = kk * 32 + (l >> 4) * 8 + j;
            Whhf[p] = (unsigned short)f2bf(W_hh[(size_t)row * HD + col]);
        } else {
            int p = q - NIH - NHH;
            int w = p / (8 * 512), rem = p % (8 * 512);
            int kk = rem / 512, li = rem % 512;
            int l = li >> 3, j = li & 7;
            int row = w * 16 + (l & 15);
            int col = kk * 32 + (l >> 4) * 8 + j;
            Wp1f[p] = (unsigned short)f2bf(W_p1[(size_t)row * (2 * HD) + col]);
        }
    }
}

// ---- MFMA GRU on packed A + winner scatter ----
// 8 waves; wave w owns units 16w..16w+15 for 32 events (2 column tiles of 16).
__global__ __launch_bounds__(512) void gru_kernel(
    const unsigned short* __restrict__ A_pack,
    const int* __restrict__ src, const int* __restrict__ dst,
    const unsigned short* __restrict__ Wihf, const unsigned short* __restrict__ Whhf,
    const float* __restrict__ b_ih, const float* __restrict__ b_hh,
    const unsigned char* __restrict__ win, float* __restrict__ mem_out)
{
    __shared__ unsigned short a_lds[EB * KP];        // 22528 B
    const int tid = threadIdx.x;
    const int e0  = blockIdx.x * EB;

    // ---- stage A-tile: contiguous coalesced copy ----
    {
        const uint4* g4 = (const uint4*)(A_pack + (size_t)e0 * KP);
        uint4* l4 = (uint4*)a_lds;
        for (int i = tid; i < EB * KP / 8; i += 512)   // 1408 uint4
            l4[i] = g4[i];
    }
    __syncthreads();

    const int w    = tid >> 6;
    const int lane = tid & 63;
    const int lg   = lane >> 4;
    const int u    = w * 16 + (lane & 15);           // output unit
    const int arow = lane & 15;

#define ALD(t, kkk) (*(const bf16x8*)&a_lds[(arow + (t) * 16) * KP + (kkk) * 32 + lg * 8])

    f32x4 z4 = {0.f, 0.f, 0.f, 0.f};
    f32x4 ir0 = z4, ir1 = z4, iz0 = z4, iz1 = z4, in0 = z4, in1 = z4;
    f32x4 sr0 = z4, sr1 = z4, sz0 = z4, sz1 = z4, sn0 = z4, sn1 = z4;
    f32x4 dr0 = z4, dr1 = z4, dz0 = z4, dz1 = z4, dn0 = z4, dn1 = z4;

#pragma unroll
    for (int kk = 0; kk < KS; ++kk) {   // gi = inp @ W_ih^T
        bf16x8 b0 = *(const bf16x8*)&Wihf[(((size_t)(0 * 8 + w) * KS + kk) * 64 + lane) * 8];
        bf16x8 b1 = *(const bf16x8*)&Wihf[(((size_t)(1 * 8 + w) * KS + kk) * 64 + lane) * 8];
        bf16x8 b2 = *(const bf16x8*)&Wihf[(((size_t)(2 * 8 + w) * KS + kk) * 64 + lane) * 8];
        bf16x8 a0 = ALD(0, kk), a1 = ALD(1, kk);
        ir0 = __builtin_amdgcn_mfma_f32_16x16x32_bf16(a0, b0, ir0, 0, 0, 0);
        ir1 = __builtin_amdgcn_mfma_f32_16x16x32_bf16(a1, b0, ir1, 0, 0, 0);
        iz0 = __builtin_amdgcn_mfma_f32_16x16x32_bf16(a0, b1, iz0, 0, 0, 0);
        iz1 = __builtin_amdgcn_mfma_f32_16x16x32_bf16(a1, b1, iz1, 0, 0, 0);
        in0 = __builtin_amdgcn_mfma_f32_16x16x32_bf16(a0, b2, in0, 0, 0, 0);
        in1 = __builtin_amdgcn_mfma_f32_16x16x32_bf16(a1, b2, in1, 0, 0, 0);
    }
#pragma unroll
    for (int kk = 0; kk < 4; ++kk) {    // gh_s (A=s) and gh_d (A=d) share W_hh frags
        bf16x8 c0 = *(const bf16x8*)&Whhf[(((size_t)(0 * 8 + w) * 4 + kk) * 64 + lane) * 8];
        bf16x8 c1 = *(const bf16x8*)&Whhf[(((size_t)(1 * 8 + w) * 4 + kk) * 64 + lane) * 8];
        bf16x8 c2 = *(const bf16x8*)&Whhf[(((size_t)(2 * 8 + w) * 4 + kk) * 64 + lane) * 8];
        bf16x8 as0 = ALD(0, kk),     as1 = ALD(1, kk);
        bf16x8 ad0 = ALD(0, kk + 4), ad1 = ALD(1, kk + 4);
        sr0 = __builtin_amdgcn_mfma_f32_16x16x32_bf16(as0, c0, sr0, 0, 0, 0);
        sr1 = __builtin_amdgcn_mfma_f32_16x16x32_bf16(as1, c0, sr1, 0, 0, 0);
        dr0 = __builtin_amdgcn_mfma_f32_16x16x32_bf16(ad0, c0, dr0, 0, 0, 0);
        dr1 = __builtin_amdgcn_mfma_f32_16x16x32_bf16(ad1, c0, dr1, 0, 0, 0);
        sz0 = __builtin_amdgcn_mfma_f32_16x16x32_bf16(as0, c1, sz0, 0, 0, 0);
        sz1 = __builtin_amdgcn_mfma_f32_16x16x32_bf16(as1, c1, sz1, 0, 0, 0);
        dz0 = __builtin_amdgcn_mfma_f32_16x16x32_bf16(ad0, c1, dz0, 0, 0, 0);
        dz1 = __builtin_amdgcn_mfma_f32_16x16x32_bf16(ad1, c1, dz1, 0, 0, 0);
        sn0 = __builtin_amdgcn_mfma_f32_16x16x32_bf16(as0, c2, sn0, 0, 0, 0);
        sn1 = __builtin_amdgcn_mfma_f32_16x16x32_bf16(as1, c2, sn1, 0, 0, 0);
        dn0 = __builtin_amdgcn_mfma_f32_16x16x32_bf16(ad0, c2, dn0, 0, 0, 0);
        dn1 = __builtin_amdgcn_mfma_f32_16x16x32_bf16(ad1, c2, dn1, 0, 0, 0);
    }
#undef ALD

    // ---- GRU nonlinearity (native exp/rcp) + winner scatter ----
    const float bir = b_ih[u], biz = b_ih[u + 128], bin_ = b_ih[u + 256];
    const float bhr = b_hh[u], bhz = b_hh[u + 128], bhn = b_hh[u + 256];

    auto epilogue = [&](int t, f32x4 ir, f32x4 iz, f32x4 in_,
                        f32x4 sr, f32x4 sz, f32x4 sn,
                        f32x4 dr, f32x4 dz, f32x4 dn) {
#pragma unroll
        for (int j = 0; j < 4; ++j) {
            int el = t * 16 + lg * 4 + j, e = e0 + el;   // C/D: row=(lane>>4)*4+reg
            unsigned char wf = win[e];
            float gr_ = ir[j] + bir, gz_ = iz[j] + biz, gn_ = in_[j] + bin_;
            if (wf & 1) {   // src update wins
                float r = fsig(gr_ + sr[j] + bhr);
                float z = fsig(gz_ + sz[j] + bhz);
                float n = ftanh(gn_ + r * (sn[j] + bhn));
                float h = bf2f(a_lds[el * KP + u]);
                mem_out[(size_t)src[e] * HD + u] = (1.f - z) * n + z * h;
            }
            if (wf & 2) {   // dst update wins
                float r = fsig(gr_ + dr[j] + bhr);
                float z = fsig(gz_ + dz[j] + bhz);
                float n = ftanh(gn_ + r * (dn[j] + bhn));
                float h = bf2f(a_lds[el * KP + 128 + u]);
                mem_out[(size_t)dst[e] * HD + u] = (1.f - z) * n + z * h;
            }
        }
    };
    epilogue(0, ir0, iz0, in0, sr0, sz0, sn0, dr0, dz0, dn0);
    epilogue(1, ir1, iz1, in1, sr1, sz1, sn1, dr1, dz1, dn1);
}

// ---------------- MFMA predictor on updated memory ----------------
__global__ __launch_bounds__(512) void pred_kernel(
    const float* __restrict__ mem,
    const int* __restrict__ src, const int* __restrict__ dst,
    const unsigned short* __restrict__ Wp1f, const float* __restrict__ b_p1,
    const float* __restrict__ W_p2, const float* __restrict__ b_p2,
    float* __restrict__ pred)
{
    __shared__ unsigned short h_lds[32 * PS];        // 16896 B
    __shared__ float partial[32][8];
    const int tid = threadIdx.x;
    const int e0  = blockIdx.x * 32;

    // stage h = [mem[src] | mem[dst]] as bf16
    for (int idx = tid; idx < 32 * 64; idx += 512) {
        int e = idx >> 6, p = idx & 63;
        const float4* row = (p < 32) ? (const float4*)&mem[(size_t)src[e0 + e] * HD]
                                     : (const float4*)&mem[(size_t)dst[e0 + e] * HD];
        float4 v = row[p & 31];
        int col = (p < 32 ? 0 : 128) + (p & 31) * 4;
        uint2 q;
        q.x = f2bf(v.x) | (f2bf(v.y) << 16);
        q.y = f2bf(v.z) | (f2bf(v.w) << 16);
        *(uint2*)&h_lds[e * PS + col] = q;
    }
    __syncthreads();

    const int w    = tid >> 6;
    const int lane = tid & 63;
    const int lg   = lane >> 4;
    const int u    = w * 16 + (lane & 15);

    f32x4 p0 = {0.f, 0.f, 0.f, 0.f}, p1 = p0;
#pragma unroll
    for (int kk = 0; kk < 8; ++kk) {
        bf16x8 b  = *(const bf16x8*)&Wp1f[(((size_t)w * 8 + kk) * 64 + lane) * 8];
        bf16x8 a0 = *(const bf16x8*)&h_lds[(lane & 15) * PS + kk * 32 + lg * 8];
        bf16x8 a1 = *(const bf16x8*)&h_lds[((lane & 15) + 16) * PS + kk * 32 + lg * 8];
        p0 = __builtin_amdgcn_mfma_f32_16x16x32_bf16(a0, b, p0, 0, 0, 0);
        p1 = __builtin_amdgcn_mfma_f32_16x16x32_bf16(a1, b, p1, 0, 0, 0);
    }
    const float bp = b_p1[u], w2 = W_p2[u];

    auto reduce_tile = [&](int t, f32x4 acc) {
#pragma unroll
        for (int j = 0; j < 4; ++j) {
            float v = acc[j] + bp;
            v = (v > 0.f ? v : 0.f) * w2;
            v += __shfl_xor(v, 1, 64);
            v += __shfl_xor(v, 2, 64);
            v += __shfl_xor(v, 4, 64);
            v += __shfl_xor(v, 8, 64);
            if ((lane & 15) == 0) partial[t * 16 + lg * 4 + j][w] = v;
        }
    };
    reduce_tile(0, p0);
    reduce_tile(1, p1);
    __syncthreads();

    if (tid < 32) {
        float s = b_p2[0];
#pragma unroll
        for (int q = 0; q < 8; ++q) s += partial[tid][q];
        pred[e0 + tid] = s;
    }
}

extern "C" void kernel_launch(void* const* d_in, const int* in_sizes, int n_in,
                              void* d_out, int out_size, void* d_ws, size_t ws_size,
                              hipStream_t stream) {
    const float* memory = (const float*)d_in[0];
    const int*   src    = (const int*)d_in[1];
    const int*   dst    = (const int*)d_in[2];
    const float* ts     = (const float*)d_in[3];
    const float* ef     = (const float*)d_in[4];
    const float* W_time = (const float*)d_in[5];
    const float* b_time = (const float*)d_in[6];
    const float* W_ih   = (const float*)d_in[7];
    const float* W_hh   = (const float*)d_in[8];
    const float* b_ih   = (const float*)d_in[9];
    const float* b_hh   = (const float*)d_in[10];
    const float* W_p1   = (const float*)d_in[11];
    const float* b_p1   = (const float*)d_in[12];
    const float* W_p2   = (const float*)d_in[13];
    const float* b_p2   = (const float*)d_in[14];

    float* pred    = (float*)d_out;                 // [NE]
    float* mem_out = pred + NE;                     // [NN, HD]

    char* ws = (char*)d_ws;
    int* prio            = (int*)ws;                ws += (size_t)NN * 4;
    unsigned short* Wihf = (unsigned short*)ws;     ws += (size_t)NIH * 2;
    unsigned short* Whhf = (unsigned short*)ws;     ws += (size_t)NHH * 2;
    unsigned short* Wp1f = (unsigned short*)ws;     ws += (size_t)NP1 * 2;
    unsigned char* win   = (unsigned char*)ws;      ws += 100352;        // 16B-aligned after
    unsigned short* A_pack = (unsigned short*)ws;   // [NE][KP] bf16, ~70.4 MB

    hipMemsetAsync(prio, 0xFF, (size_t)NN * sizeof(int), stream);   // -1
    prio_kernel<<<(NE + 255) / 256, 256, 0, stream>>>(src, dst, prio);
    prep_kernel<<<NBC + NBG + NBW + NBV, 512, 0, stream>>>(
        memory, src, dst, ts, ef, W_time, b_time, W_ih, W_hh, W_p1,
        prio, win, A_pack, Wihf, Whhf, Wp1f, mem_out);
    gru_kernel<<<NBG, 512, 0, stream>>>(A_pack, src, dst, Wihf, Whhf,
                                        b_ih, b_hh, win, mem_out);
    pred_kernel<<<NE / 32, 512, 0, stream>>>(mem_out, src, dst,
                                             Wp1f, b_p1, W_p2, b_p2, pred);
}